// Round 2
// baseline (1031.304 us; speedup 1.0000x reference)
//
#include <hip/hip_runtime.h>
#include <stdint.h>

typedef unsigned short u16;
typedef __bf16 bf16x8 __attribute__((ext_vector_type(8)));
typedef float f32x4 __attribute__((ext_vector_type(4)));

// Geometry
// x: [8, 512, 100, 100] (NCHW). Padded spatial grid: 102x102, flat p in [0,10404).
// xt: channels-last padded input [b][row][c] bf16, row = 128-guard + p, per-batch stride 10752 rows.
// feat: [b][p][o] bf16, per-batch stride 10496 rows (82 n-tiles * 128).
#define XT_STRIDE 10752
#define XT_GUARD  128
#define NPAD      10496
#define NT        82

__device__ __forceinline__ float b2f(u16 u) {
  union { unsigned int i; float f; } v; v.i = ((unsigned int)u) << 16; return v.f;
}
__device__ __forceinline__ u16 f2b(float f) {
  union { float f; unsigned int i; } v; v.f = f;
  unsigned int u = v.i;
  unsigned int r = u + 0x7FFFu + ((u >> 16) & 1u);  // RNE, finite inputs
  return (u16)(r >> 16);
}
// dual-dtype input read: flag32 ? f32 : bf16
__device__ __forceinline__ float ldin(const void* p, long i, int f32) {
  return f32 ? ((const float*)p)[i] : b2f(((const u16*)p)[i]);
}

// ---------------- P0: input dtype sniffer ----------------
// bf16 N(0,1) data: no u16 has exponent field 0xFF. f32 data read as u16:
// low halves are ~uniform bits -> ~1/256 have exp 0xFF. Count over 64K u16.
__global__ __launch_bounds__(256) void k_sniff(const u16* __restrict__ x, int* __restrict__ flag) {
  __shared__ int cnt;
  if (threadIdx.x == 0) cnt = 0;
  __syncthreads();
  int c = 0;
  for (int i = threadIdx.x; i < 65536; i += 256) {
    u16 v = x[i];
    if (((v >> 7) & 0xFF) == 0xFF) c++;
  }
  atomicAdd(&cnt, c);
  __syncthreads();
  if (threadIdx.x == 0) *flag = (cnt >= 4) ? 1 : 0;
}

// ---------------- P1: NCHW -> padded channels-last bf16 ----------------
__global__ __launch_bounds__(256) void k_transpose(const void* __restrict__ x,
                                                   u16* __restrict__ xt,
                                                   const int* __restrict__ flag) {
  __shared__ u16 sT[64 * 101];
  const int f32 = *flag;
  const int t = threadIdx.x;
  const int cb = blockIdx.x, h = blockIdx.y, b = blockIdx.z;
  const int c0 = cb * 64;
  const long sbase = (long)(b * 512 + c0) * 10000 + h * 100;
  #pragma unroll
  for (int i = 0; i < 25; ++i) {
    int idx = i * 256 + t;
    int c = idx / 100, w = idx - c * 100;
    sT[c * 101 + w] = f2b(ldin(x, sbase + (long)c * 10000 + w, f32));
  }
  __syncthreads();
  // p = (h+1)*102 + (w+1); interior only, pads stay memset-zero
  u16* dst = xt + ((long)b * XT_STRIDE + XT_GUARD + (h + 1) * 102 + 1) * 512 + c0;
  #pragma unroll
  for (int i = 0; i < 25; ++i) {
    int idx = i * 256 + t;
    int w = idx >> 6, c = idx & 63;
    dst[(long)w * 512 + c] = sT[c * 101 + w];
  }
}

// ---------------- P2: w_rpn [o][c][3][3] -> wA [o][ s*512 + c ] bf16 ----------------
__global__ __launch_bounds__(256) void k_wA(const void* __restrict__ w_rpn,
                                            u16* __restrict__ wA,
                                            const int* __restrict__ flag) {
  const int f32 = *flag;
  const int idx = blockIdx.x * 256 + threadIdx.x;  // o*512 + c, < 262144
  const int o = idx >> 9, c = idx & 511;
  u16* dst = wA + (long)o * 4608 + c;
  #pragma unroll
  for (int s = 0; s < 9; ++s) dst[s * 512] = f2b(ldin(w_rpn, (long)idx * 9 + s, f32));
}

// ---------------- P3: head weights [48][512] bf16 + all biases fp32 ----------------
// bAll[0..511] = b_rpn; bAll[512+a] = head bias a (a<9: cls, 9..44: bbox, 45..47: 0)
__global__ __launch_bounds__(256) void k_wH(const void* __restrict__ w_cls, const void* __restrict__ b_cls,
                                            const void* __restrict__ w_bbox, const void* __restrict__ b_bbox,
                                            const void* __restrict__ b_rpn,
                                            u16* __restrict__ wH, float* __restrict__ bAll,
                                            const int* __restrict__ flag) {
  const int f32 = *flag;
  const int idx = blockIdx.x * 256 + threadIdx.x;  // < 24576
  const int a = idx >> 9, c = idx & 511;
  float v = 0.f;
  if (a < 9) v = ldin(w_cls, a * 512 + c, f32);
  else if (a < 45) v = ldin(w_bbox, (a - 9) * 512 + c, f32);
  wH[idx] = f2b(v);
  if (idx < 512) bAll[idx] = ldin(b_rpn, idx, f32);
  if (c == 0) {
    float bv = 0.f;
    if (a < 9) bv = ldin(b_cls, a, f32);
    else if (a < 45) bv = ldin(b_bbox, a - 9, f32);
    bAll[512 + a] = bv;
  }
}

// ---------------- Conv as implicit GEMM: feat[p][o] = relu(wA . im2col + b) ----------------
// 128x128 tile, BK=32; register staging (uint4 global->reg->LDS), m97 fragment layout.
__global__ __launch_bounds__(256) void k_conv(const u16* __restrict__ xt, const u16* __restrict__ wA,
                                              const float* __restrict__ bAll, u16* __restrict__ feat) {
  __shared__ u16 sA[128 * 32];   // [o_local][k] 8 KB
  __shared__ u16 sB[128 * 32];   // [n_local][k] 8 KB
  __shared__ float sBias[128];
  const int t = threadIdx.x;
  const int nt = blockIdx.x, mt = blockIdx.y, b = blockIdx.z;
  const int m0 = mt * 128, n0 = nt * 128;
  if (t < 128) sBias[t] = bAll[m0 + t];
  f32x4 acc[4][4] = {};
  const int lane = t & 63, wv = t >> 6;
  const int row = t >> 2, seg = (t & 3) * 8;       // staging: row=t/4, 8-elem segment
  const int mh = (wv & 1) * 64, nh = (wv >> 1) * 64;
  const int l15 = lane & 15, q = lane >> 4;
  char* sAb = (char*)sA;
  char* sBb = (char*)sB;
  const u16* gA = wA + (long)(m0 + row) * 4608 + seg;
  const u16* xtb = xt + ((long)b * XT_STRIDE + XT_GUARD) * 512;
  const u16* pa = sA + (mh + l15) * 32 + q * 8;    // A frag: [m=lane&15][k=q*8+j]
  const u16* pb = sB + (nh + l15) * 32 + q * 8;    // B frag: [n=lane&15][k=q*8+j]
  for (int ks = 0; ks < 144; ++ks) {
    const int k0 = ks * 32;
    const int s = ks >> 4;                          // shift index 0..8
    const int c0 = k0 & 511;
    const int off = (s / 3) * 102 + (s - (s / 3) * 3) - 103;  // (dh-1)*102 + (dw-1)
    const u16* gB = xtb + (long)(n0 + row + off) * 512 + c0 + seg;
    uint4 a0 = *(const uint4*)(gA + k0);
    uint4 a1 = *(const uint4*)(gA + k0 + (long)64 * 4608);
    uint4 b0 = *(const uint4*)(gB);
    uint4 b1 = *(const uint4*)(gB + 64 * 512);
    *(uint4*)(sAb + t * 16) = a0;
    *(uint4*)(sAb + 4096 + t * 16) = a1;
    *(uint4*)(sBb + t * 16) = b0;
    *(uint4*)(sBb + 4096 + t * 16) = b1;
    __syncthreads();
    bf16x8 af[4], bf[4];
    #pragma unroll
    for (int i = 0; i < 4; ++i) af[i] = *(const bf16x8*)(pa + i * 512);
    #pragma unroll
    for (int i = 0; i < 4; ++i) bf[i] = *(const bf16x8*)(pb + i * 512);
    #pragma unroll
    for (int mi = 0; mi < 4; ++mi)
      #pragma unroll
      for (int ni = 0; ni < 4; ++ni)
        acc[mi][ni] = __builtin_amdgcn_mfma_f32_16x16x32_bf16(af[mi], bf[ni], acc[mi][ni], 0, 0, 0);
    __syncthreads();
  }
  // epilogue: bias + relu, store feat channels-last (4 consecutive o per lane -> 8B store)
  u16* fb = feat + (long)b * NPAD * 512;
  #pragma unroll
  for (int mi = 0; mi < 4; ++mi) {
    const int ol = mh + mi * 16 + q * 4;
    #pragma unroll
    for (int ni = 0; ni < 4; ++ni) {
      const int p = n0 + nh + ni * 16 + l15;
      unsigned long long pk = 0;
      #pragma unroll
      for (int r = 0; r < 4; ++r) {
        float v = acc[mi][ni][r] + sBias[ol + r];
        v = v > 0.f ? v : 0.f;
        pk |= ((unsigned long long)f2b(v)) << (16 * r);
      }
      *(unsigned long long*)(fb + (long)p * 512 + m0 + ol) = pk;
    }
  }
}

// ---------------- Heads: [48x512] x [512 x Ntile] MFMA GEMM, masked dual-dtype store ----------------
__global__ __launch_bounds__(256) void k_head(const u16* __restrict__ feat, const u16* __restrict__ wH,
                                              const float* __restrict__ bAll, void* __restrict__ out,
                                              const int* __restrict__ flag) {
  __shared__ u16 sA[48 * 32];    // 3 KB
  __shared__ u16 sB[128 * 32];   // 8 KB
  const int f32 = *flag;
  const int t = threadIdx.x;
  const int nt = blockIdx.x, b = blockIdx.y;
  const int n0 = nt * 128;
  f32x4 acc[3][2] = {};
  const int lane = t & 63, wv = t >> 6;
  const int row = t >> 2, seg = (t & 3) * 8;
  const int l15 = lane & 15, q = lane >> 4;
  const u16* fbase = feat + (long)b * NPAD * 512;
  const u16* pa = sA + l15 * 32 + q * 8;
  const u16* pb = sB + (wv * 32 + l15) * 32 + q * 8;  // each wave owns 32 n's
  char* sAb = (char*)sA;
  char* sBb = (char*)sB;
  for (int ks = 0; ks < 16; ++ks) {
    const int k0 = ks * 32;
    const u16* gB = fbase + (long)(n0 + row) * 512 + k0 + seg;
    uint4 b0 = *(const uint4*)(gB);
    uint4 b1 = *(const uint4*)(gB + 64 * 512);
    if (t < 192) {
      uint4 a0 = *(const uint4*)(wH + (long)row * 512 + k0 + seg);
      *(uint4*)(sAb + t * 16) = a0;
    }
    *(uint4*)(sBb + t * 16) = b0;
    *(uint4*)(sBb + 4096 + t * 16) = b1;
    __syncthreads();
    bf16x8 af[3], bf[2];
    #pragma unroll
    for (int i = 0; i < 3; ++i) af[i] = *(const bf16x8*)(pa + i * 512);
    #pragma unroll
    for (int i = 0; i < 2; ++i) bf[i] = *(const bf16x8*)(pb + i * 512);
    #pragma unroll
    for (int mi = 0; mi < 3; ++mi)
      #pragma unroll
      for (int ni = 0; ni < 2; ++ni)
        acc[mi][ni] = __builtin_amdgcn_mfma_f32_16x16x32_bf16(af[mi], bf[ni], acc[mi][ni], 0, 0, 0);
    __syncthreads();
  }
  #pragma unroll
  for (int ni = 0; ni < 2; ++ni) {
    const int p = n0 + wv * 32 + ni * 16 + l15;
    const int pr = p / 102, pc = p - pr * 102;
    if (pr < 1 || pr > 100 || pc < 1 || pc > 100) continue;  // pad position
    const int h = pr - 1, w = pc - 1;
    #pragma unroll
    for (int mi = 0; mi < 3; ++mi) {
      #pragma unroll
      for (int r = 0; r < 4; ++r) {
        const int a = mi * 16 + q * 4 + r;
        if (a >= 45) continue;
        float v = acc[mi][ni][r] + bAll[512 + a];
        long oidx;
        if (a < 9) oidx = ((long)(b * 9 + a)) * 10000 + h * 100 + w;
        else       oidx = 720000 + ((long)(b * 36 + (a - 9))) * 10000 + h * 100 + w;
        if (f32) ((float*)out)[oidx] = v;
        else     ((u16*)out)[oidx] = f2b(v);
      }
    }
  }
}

extern "C" void kernel_launch(void* const* d_in, const int* in_sizes, int n_in,
                              void* d_out, int out_size, void* d_ws, size_t ws_size,
                              hipStream_t stream) {
  const void* x      = d_in[0];
  const void* w_rpn  = d_in[1];
  const void* b_rpn  = d_in[2];
  const void* w_cls  = d_in[3];
  const void* b_cls  = d_in[4];
  const void* w_bbox = d_in[5];
  const void* b_bbox = d_in[6];
  char* ws = (char*)d_ws;
  // workspace layout (bytes)
  u16*  xt   = (u16*) (ws);                 // 8*10752*512*2 = 88,080,384
  u16*  feat = (u16*) (ws + 88080384);      // 8*10496*512*2 = 85,983,232
  u16*  wA   = (u16*) (ws + 174063616);     // 512*4608*2    =  4,718,592
  u16*  wH   = (u16*) (ws + 178782208);     // 48*512*2      =     49,152
  float* bAll= (float*)(ws + 178831360);    // 560*4         =      2,240
  int*  flag = (int*) (ws + 178833600);     // 4

  k_sniff<<<1, 256, 0, stream>>>((const u16*)x, flag);
  hipMemsetAsync(xt, 0, 88080384, stream);                       // zero pads + guards
  k_transpose<<<dim3(8, 100, 8), 256, 0, stream>>>(x, xt, flag);
  k_wA<<<1024, 256, 0, stream>>>(w_rpn, wA, flag);
  k_wH<<<96, 256, 0, stream>>>(w_cls, b_cls, w_bbox, b_bbox, b_rpn, wH, bAll, flag);
  k_conv<<<dim3(NT, 4, 8), 256, 0, stream>>>(xt, wA, bAll, feat);
  k_head<<<dim3(NT, 8), 256, 0, stream>>>(feat, wH, bAll, (void*)d_out, flag);
}

// Round 3
// 853.703 us; speedup vs baseline: 1.2080x; 1.2080x over previous
//
#include <hip/hip_runtime.h>
#include <stdint.h>

typedef unsigned short u16;
typedef __bf16 bf16x8 __attribute__((ext_vector_type(8)));
typedef float f32x4 __attribute__((ext_vector_type(4)));

// Geometry
// x: [8, 512, 100, 100] (NCHW). Padded spatial grid: 102x102, flat p in [0,10404).
// xt: channels-last padded input [b][row][c] bf16, row = 128-guard + p, per-batch stride 10752 rows.
// feat: [b][p][o] bf16, per-batch stride 10496 rows (82 n-tiles * 128).
#define XT_STRIDE 10752
#define XT_GUARD  128
#define NPAD      10496
#define NT        82

__device__ __forceinline__ float b2f(u16 u) {
  union { unsigned int i; float f; } v; v.i = ((unsigned int)u) << 16; return v.f;
}
__device__ __forceinline__ u16 f2b(float f) {
  union { float f; unsigned int i; } v; v.f = f;
  unsigned int u = v.i;
  unsigned int r = u + 0x7FFFu + ((u >> 16) & 1u);  // RNE, finite inputs
  return (u16)(r >> 16);
}
// dual-dtype input read: flag32 ? f32 : bf16
__device__ __forceinline__ float ldin(const void* p, long i, int f32) {
  return f32 ? ((const float*)p)[i] : b2f(((const u16*)p)[i]);
}
// async global->LDS, 16B per lane; LDS dest = wave-uniform base + lane*16
__device__ __forceinline__ void async16(const void* g, void* l) {
  __builtin_amdgcn_global_load_lds(
      (const __attribute__((address_space(1))) unsigned int*)g,
      (__attribute__((address_space(3))) unsigned int*)l, 16, 0, 0);
}

// ---------------- P0: input dtype sniffer ----------------
__global__ __launch_bounds__(256) void k_sniff(const u16* __restrict__ x, int* __restrict__ flag) {
  __shared__ int cnt;
  if (threadIdx.x == 0) cnt = 0;
  __syncthreads();
  int c = 0;
  for (int i = threadIdx.x; i < 65536; i += 256) {
    u16 v = x[i];
    if (((v >> 7) & 0xFF) == 0xFF) c++;
  }
  atomicAdd(&cnt, c);
  __syncthreads();
  if (threadIdx.x == 0) *flag = (cnt >= 4) ? 1 : 0;
}

// ---------------- P1: NCHW -> padded channels-last bf16 (vectorized) ----------------
// Block (cb,h,b): 128-channel slab of one row h. LDS tile [w][c] so global stores are uint4.
__global__ __launch_bounds__(256) void k_transpose(const void* __restrict__ x,
                                                   u16* __restrict__ xt,
                                                   const int* __restrict__ flag) {
  __shared__ u16 sW[100 * 136];  // [w][c-slab], pad 136 (272B rows: 16B-aligned)
  const int f32 = *flag;
  const int t = threadIdx.x;
  const int cb = blockIdx.x, h = blockIdx.y, b = blockIdx.z;
  const int c0 = cb * 128;
  if (!f32) {
    const u16* src = (const u16*)x + (long)(b * 512 + c0) * 10000 + h * 100;
    for (int i = t; i < 128 * 25; i += 256) {
      int c = i / 25, j = i - c * 25;           // j-th uint2 (4 u16) of channel-row c
      uint2 v = *(const uint2*)(src + (long)c * 10000 + j * 4);
      u16* d = sW + (j * 4) * 136 + c;
      const u16* pv = (const u16*)&v;
      d[0] = pv[0]; d[136] = pv[1]; d[272] = pv[2]; d[408] = pv[3];
    }
  } else {
    const float* src = (const float*)x + (long)(b * 512 + c0) * 10000 + h * 100;
    for (int i = t; i < 128 * 25; i += 256) {
      int c = i / 25, j = i - c * 25;
      float4 v = *(const float4*)(src + (long)c * 10000 + j * 4);
      u16* d = sW + (j * 4) * 136 + c;
      d[0] = f2b(v.x); d[136] = f2b(v.y); d[272] = f2b(v.z); d[408] = f2b(v.w);
    }
  }
  __syncthreads();
  // p = (h+1)*102 + (w+1); interior only, pads stay memset-zero
  u16* dst = xt + ((long)b * XT_STRIDE + XT_GUARD + (h + 1) * 102 + 1) * 512 + c0;
  for (int i = t; i < 100 * 16; i += 256) {
    int w = i >> 4, sub = i & 15;
    uint4 v = *(const uint4*)(sW + w * 136 + sub * 8);
    *(uint4*)(dst + (long)w * 512 + sub * 8) = v;
  }
}

// ---------------- P2: w_rpn [o][c][3][3] -> wA [o][ s*512 + c ] bf16 ----------------
__global__ __launch_bounds__(256) void k_wA(const void* __restrict__ w_rpn,
                                            u16* __restrict__ wA,
                                            const int* __restrict__ flag) {
  const int f32 = *flag;
  const int idx = blockIdx.x * 256 + threadIdx.x;  // o*512 + c, < 262144
  const int o = idx >> 9, c = idx & 511;
  u16* dst = wA + (long)o * 4608 + c;
  #pragma unroll
  for (int s = 0; s < 9; ++s) dst[s * 512] = f2b(ldin(w_rpn, (long)idx * 9 + s, f32));
}

// ---------------- P3: head weights [48][512] bf16 + all biases fp32 ----------------
__global__ __launch_bounds__(256) void k_wH(const void* __restrict__ w_cls, const void* __restrict__ b_cls,
                                            const void* __restrict__ w_bbox, const void* __restrict__ b_bbox,
                                            const void* __restrict__ b_rpn,
                                            u16* __restrict__ wH, float* __restrict__ bAll,
                                            const int* __restrict__ flag) {
  const int f32 = *flag;
  const int idx = blockIdx.x * 256 + threadIdx.x;  // < 24576
  const int a = idx >> 9, c = idx & 511;
  float v = 0.f;
  if (a < 9) v = ldin(w_cls, a * 512 + c, f32);
  else if (a < 45) v = ldin(w_bbox, (a - 9) * 512 + c, f32);
  wH[idx] = f2b(v);
  if (idx < 512) bAll[idx] = ldin(b_rpn, idx, f32);
  if (c == 0) {
    float bv = 0.f;
    if (a < 9) bv = ldin(b_cls, a, f32);
    else if (a < 45) bv = ldin(b_bbox, a - 9, f32);
    bAll[512 + a] = bv;
  }
}

// ---------------- Conv as implicit GEMM: feat[p][o] = relu(wA . im2col + b) ----------------
// 128x128 tile, BK=32; global_load_lds width-16 staging (m97 structure).
// LDS data mapping is byte-identical to the proven register-staging version:
// dest(wave wv, lane l) = base wv*1024 + l*16 bytes == old sAb + t*16.
__global__ __launch_bounds__(256) void k_conv(const u16* __restrict__ xt, const u16* __restrict__ wA,
                                              const float* __restrict__ bAll, u16* __restrict__ feat) {
  __shared__ u16 sA[128 * 32];   // [o_local][k] 8 KB
  __shared__ u16 sB[128 * 32];   // [n_local][k] 8 KB
  __shared__ float sBias[128];
  const int t = threadIdx.x;
  const int nt = blockIdx.x, mt = blockIdx.y, b = blockIdx.z;
  const int m0 = mt * 128, n0 = nt * 128;
  if (t < 128) sBias[t] = bAll[m0 + t];
  f32x4 acc[4][4] = {};
  const int lane = t & 63, wv = t >> 6;
  const int row = t >> 2, seg = (t & 3) * 8;       // staging: row=t/4, 8-elem segment
  const int mh = (wv & 1) * 64, nh = (wv >> 1) * 64;
  const int l15 = lane & 15, q = lane >> 4;
  u16* sAw = sA + wv * 512;                        // wave-uniform LDS base (bytes wv*1024)
  u16* sBw = sB + wv * 512;
  const u16* gA = wA + (long)(m0 + row) * 4608 + seg;
  const u16* xtb = xt + ((long)b * XT_STRIDE + XT_GUARD) * 512;
  const u16* pa = sA + (mh + l15) * 32 + q * 8;    // A frag: [m=lane&15][k=q*8+j]
  const u16* pb = sB + (nh + l15) * 32 + q * 8;    // B frag: [n=lane&15][k=q*8+j]
  for (int ks = 0; ks < 144; ++ks) {
    const int k0 = ks * 32;
    const int s = ks >> 4;                          // shift index 0..8
    const int c0 = k0 & 511;
    const int off = (s / 3) * 102 + (s - (s / 3) * 3) - 103;  // (dh-1)*102 + (dw-1)
    const u16* gB = xtb + (long)(n0 + row + off) * 512 + c0 + seg;
    async16(gA + k0, sAw);
    async16(gA + k0 + (long)64 * 4608, sAw + 2048);
    async16(gB, sBw);
    async16(gB + 64 * 512, sBw + 2048);
    asm volatile("s_waitcnt vmcnt(0)" ::: "memory");  // drain async-LDS before barrier
    __syncthreads();
    bf16x8 af[4], bf[4];
    #pragma unroll
    for (int i = 0; i < 4; ++i) af[i] = *(const bf16x8*)(pa + i * 512);
    #pragma unroll
    for (int i = 0; i < 4; ++i) bf[i] = *(const bf16x8*)(pb + i * 512);
    #pragma unroll
    for (int mi = 0; mi < 4; ++mi)
      #pragma unroll
      for (int ni = 0; ni < 4; ++ni)
        acc[mi][ni] = __builtin_amdgcn_mfma_f32_16x16x32_bf16(af[mi], bf[ni], acc[mi][ni], 0, 0, 0);
    __syncthreads();
  }
  // epilogue: bias + relu, store feat channels-last (4 consecutive o per lane -> 8B store)
  u16* fb = feat + (long)b * NPAD * 512;
  #pragma unroll
  for (int mi = 0; mi < 4; ++mi) {
    const int ol = mh + mi * 16 + q * 4;
    #pragma unroll
    for (int ni = 0; ni < 4; ++ni) {
      const int p = n0 + nh + ni * 16 + l15;
      unsigned long long pk = 0;
      #pragma unroll
      for (int r = 0; r < 4; ++r) {
        float v = acc[mi][ni][r] + sBias[ol + r];
        v = v > 0.f ? v : 0.f;
        pk |= ((unsigned long long)f2b(v)) << (16 * r);
      }
      *(unsigned long long*)(fb + (long)p * 512 + m0 + ol) = pk;
    }
  }
}

// ---------------- Heads: [48x512] x [512 x Ntile] MFMA GEMM, masked dual-dtype store ----------------
__global__ __launch_bounds__(256) void k_head(const u16* __restrict__ feat, const u16* __restrict__ wH,
                                              const float* __restrict__ bAll, void* __restrict__ out,
                                              const int* __restrict__ flag) {
  __shared__ u16 sA[48 * 32];    // 3 KB
  __shared__ u16 sB[128 * 32];   // 8 KB
  const int f32 = *flag;
  const int t = threadIdx.x;
  const int nt = blockIdx.x, b = blockIdx.y;
  const int n0 = nt * 128;
  f32x4 acc[3][2] = {};
  const int lane = t & 63, wv = t >> 6;
  const int row = t >> 2, seg = (t & 3) * 8;
  const int l15 = lane & 15, q = lane >> 4;
  const u16* fbase = feat + (long)b * NPAD * 512;
  const u16* pa = sA + l15 * 32 + q * 8;
  const u16* pb = sB + (wv * 32 + l15) * 32 + q * 8;  // each wave owns 32 n's
  char* sAb = (char*)sA;
  char* sBb = (char*)sB;
  for (int ks = 0; ks < 16; ++ks) {
    const int k0 = ks * 32;
    const u16* gB = fbase + (long)(n0 + row) * 512 + k0 + seg;
    uint4 b0 = *(const uint4*)(gB);
    uint4 b1 = *(const uint4*)(gB + 64 * 512);
    if (t < 192) {
      uint4 a0 = *(const uint4*)(wH + (long)row * 512 + k0 + seg);
      *(uint4*)(sAb + t * 16) = a0;
    }
    *(uint4*)(sBb + t * 16) = b0;
    *(uint4*)(sBb + 4096 + t * 16) = b1;
    __syncthreads();
    bf16x8 af[3], bf[2];
    #pragma unroll
    for (int i = 0; i < 3; ++i) af[i] = *(const bf16x8*)(pa + i * 512);
    #pragma unroll
    for (int i = 0; i < 2; ++i) bf[i] = *(const bf16x8*)(pb + i * 512);
    #pragma unroll
    for (int mi = 0; mi < 3; ++mi)
      #pragma unroll
      for (int ni = 0; ni < 2; ++ni)
        acc[mi][ni] = __builtin_amdgcn_mfma_f32_16x16x32_bf16(af[mi], bf[ni], acc[mi][ni], 0, 0, 0);
    __syncthreads();
  }
  #pragma unroll
  for (int ni = 0; ni < 2; ++ni) {
    const int p = n0 + wv * 32 + ni * 16 + l15;
    const int pr = p / 102, pc = p - pr * 102;
    if (pr < 1 || pr > 100 || pc < 1 || pc > 100) continue;  // pad position
    const int h = pr - 1, w = pc - 1;
    #pragma unroll
    for (int mi = 0; mi < 3; ++mi) {
      #pragma unroll
      for (int r = 0; r < 4; ++r) {
        const int a = mi * 16 + q * 4 + r;
        if (a >= 45) continue;
        float v = acc[mi][ni][r] + bAll[512 + a];
        long oidx;
        if (a < 9) oidx = ((long)(b * 9 + a)) * 10000 + h * 100 + w;
        else       oidx = 720000 + ((long)(b * 36 + (a - 9))) * 10000 + h * 100 + w;
        if (f32) ((float*)out)[oidx] = v;
        else     ((u16*)out)[oidx] = f2b(v);
      }
    }
  }
}

extern "C" void kernel_launch(void* const* d_in, const int* in_sizes, int n_in,
                              void* d_out, int out_size, void* d_ws, size_t ws_size,
                              hipStream_t stream) {
  const void* x      = d_in[0];
  const void* w_rpn  = d_in[1];
  const void* b_rpn  = d_in[2];
  const void* w_cls  = d_in[3];
  const void* b_cls  = d_in[4];
  const void* w_bbox = d_in[5];
  const void* b_bbox = d_in[6];
  char* ws = (char*)d_ws;
  // workspace layout (bytes)
  u16*  xt   = (u16*) (ws);                 // 8*10752*512*2 = 88,080,384
  u16*  feat = (u16*) (ws + 88080384);      // 8*10496*512*2 = 85,983,232
  u16*  wA   = (u16*) (ws + 174063616);     // 512*4608*2    =  4,718,592
  u16*  wH   = (u16*) (ws + 178782208);     // 48*512*2      =     49,152
  float* bAll= (float*)(ws + 178831360);    // 560*4         =      2,240
  int*  flag = (int*) (ws + 178833600);     // 4

  k_sniff<<<1, 256, 0, stream>>>((const u16*)x, flag);
  hipMemsetAsync(xt, 0, 88080384, stream);                       // zero pads + guards
  k_transpose<<<dim3(4, 100, 8), 256, 0, stream>>>(x, xt, flag);
  k_wA<<<1024, 256, 0, stream>>>(w_rpn, wA, flag);
  k_wH<<<96, 256, 0, stream>>>(w_cls, b_cls, w_bbox, b_bbox, b_rpn, wH, bAll, flag);
  k_conv<<<dim3(NT, 4, 8), 256, 0, stream>>>(xt, wA, bAll, feat);
  k_head<<<dim3(NT, 8), 256, 0, stream>>>(feat, wH, bAll, (void*)d_out, flag);
}

// Round 4
// 815.586 us; speedup vs baseline: 1.2645x; 1.0467x over previous
//
#include <hip/hip_runtime.h>
#include <stdint.h>

typedef unsigned short u16;
typedef __bf16 bf16x8 __attribute__((ext_vector_type(8)));
typedef float f32x4 __attribute__((ext_vector_type(4)));

// Geometry
// x: [8, 512, 100, 100] (NCHW). Padded spatial grid: 102x102, flat p in [0,10404).
// xt: channels-last padded input [b][row][c] bf16, row = 128-guard + p, per-batch stride 10752 rows.
// feat: [b][p][o] bf16, per-batch stride 10496 rows (82 n-tiles * 128).
#define XT_STRIDE 10752
#define XT_GUARD  128
#define NPAD      10496
#define NT        82

__device__ __forceinline__ float b2f(u16 u) {
  union { unsigned int i; float f; } v; v.i = ((unsigned int)u) << 16; return v.f;
}
__device__ __forceinline__ u16 f2b(float f) {
  union { float f; unsigned int i; } v; v.f = f;
  unsigned int u = v.i;
  unsigned int r = u + 0x7FFFu + ((u >> 16) & 1u);  // RNE, finite inputs
  return (u16)(r >> 16);
}
__device__ __forceinline__ float ldin(const void* p, long i, int f32) {
  return f32 ? ((const float*)p)[i] : b2f(((const u16*)p)[i]);
}
// async global->LDS, 16B per lane; LDS dest = wave-uniform base + lane*16
__device__ __forceinline__ void async16(const void* g, void* l) {
  __builtin_amdgcn_global_load_lds(
      (const __attribute__((address_space(1))) unsigned int*)g,
      (__attribute__((address_space(3))) unsigned int*)l, 16, 0, 0);
}

// ---------------- P0: input dtype sniffer ----------------
__global__ __launch_bounds__(256) void k_sniff(const u16* __restrict__ x, int* __restrict__ flag) {
  __shared__ int cnt;
  if (threadIdx.x == 0) cnt = 0;
  __syncthreads();
  int c = 0;
  for (int i = threadIdx.x; i < 65536; i += 256) {
    u16 v = x[i];
    if (((v >> 7) & 0xFF) == 0xFF) c++;
  }
  atomicAdd(&cnt, c);
  __syncthreads();
  if (threadIdx.x == 0) *flag = (cnt >= 4) ? 1 : 0;
}

// ---------------- P1: NCHW -> padded channels-last bf16 (vectorized) ----------------
__global__ __launch_bounds__(256) void k_transpose(const void* __restrict__ x,
                                                   u16* __restrict__ xt,
                                                   const int* __restrict__ flag) {
  __shared__ u16 sW[100 * 136];  // [w][c-slab], pad 136 (272B rows: 16B-aligned)
  const int f32 = *flag;
  const int t = threadIdx.x;
  const int cb = blockIdx.x, h = blockIdx.y, b = blockIdx.z;
  const int c0 = cb * 128;
  if (!f32) {
    const u16* src = (const u16*)x + (long)(b * 512 + c0) * 10000 + h * 100;
    for (int i = t; i < 128 * 25; i += 256) {
      int c = i / 25, j = i - c * 25;           // j-th uint2 (4 u16) of channel-row c
      uint2 v = *(const uint2*)(src + (long)c * 10000 + j * 4);
      u16* d = sW + (j * 4) * 136 + c;
      const u16* pv = (const u16*)&v;
      d[0] = pv[0]; d[136] = pv[1]; d[272] = pv[2]; d[408] = pv[3];
    }
  } else {
    const float* src = (const float*)x + (long)(b * 512 + c0) * 10000 + h * 100;
    for (int i = t; i < 128 * 25; i += 256) {
      int c = i / 25, j = i - c * 25;
      float4 v = *(const float4*)(src + (long)c * 10000 + j * 4);
      u16* d = sW + (j * 4) * 136 + c;
      d[0] = f2b(v.x); d[136] = f2b(v.y); d[272] = f2b(v.z); d[408] = f2b(v.w);
    }
  }
  __syncthreads();
  u16* dst = xt + ((long)b * XT_STRIDE + XT_GUARD + (h + 1) * 102 + 1) * 512 + c0;
  for (int i = t; i < 100 * 16; i += 256) {
    int w = i >> 4, sub = i & 15;
    uint4 v = *(const uint4*)(sW + w * 136 + sub * 8);
    *(uint4*)(dst + (long)w * 512 + sub * 8) = v;
  }
}

// ---------------- P2: w_rpn [o][c][3][3] -> wA [o][ s*512 + c ] bf16 ----------------
__global__ __launch_bounds__(256) void k_wA(const void* __restrict__ w_rpn,
                                            u16* __restrict__ wA,
                                            const int* __restrict__ flag) {
  const int f32 = *flag;
  const int idx = blockIdx.x * 256 + threadIdx.x;  // o*512 + c, < 262144
  const int o = idx >> 9, c = idx & 511;
  u16* dst = wA + (long)o * 4608 + c;
  #pragma unroll
  for (int s = 0; s < 9; ++s) dst[s * 512] = f2b(ldin(w_rpn, (long)idx * 9 + s, f32));
}

// ---------------- P3: head weights [48][512] bf16 + all biases fp32 ----------------
__global__ __launch_bounds__(256) void k_wH(const void* __restrict__ w_cls, const void* __restrict__ b_cls,
                                            const void* __restrict__ w_bbox, const void* __restrict__ b_bbox,
                                            const void* __restrict__ b_rpn,
                                            u16* __restrict__ wH, float* __restrict__ bAll,
                                            const int* __restrict__ flag) {
  const int f32 = *flag;
  const int idx = blockIdx.x * 256 + threadIdx.x;  // < 24576
  const int a = idx >> 9, c = idx & 511;
  float v = 0.f;
  if (a < 9) v = ldin(w_cls, a * 512 + c, f32);
  else if (a < 45) v = ldin(w_bbox, (a - 9) * 512 + c, f32);
  wH[idx] = f2b(v);
  if (idx < 512) bAll[idx] = ldin(b_rpn, idx, f32);
  if (c == 0) {
    float bv = 0.f;
    if (a < 9) bv = ldin(b_cls, a, f32);
    else if (a < 45) bv = ldin(b_bbox, a - 9, f32);
    bAll[512 + a] = bv;
  }
}

// ---------------- Conv implicit GEMM: 128x128 tile, BK=64, XCD swizzle, XOR-seg LDS ----------------
// LDS tile [row][64k] = 128B rows; segment j (16B) of row r holds global segment j^(r&7)
// (staged by source-permute since global_load_lds dest is linear). Readers XOR back -> 2-way banks.
__global__ __launch_bounds__(256, 4) void k_conv(const u16* __restrict__ xt, const u16* __restrict__ wA,
                                                 const float* __restrict__ bAll, u16* __restrict__ feat) {
  __shared__ u16 sA[128 * 64];   // 16 KB
  __shared__ u16 sB[128 * 64];   // 16 KB
  __shared__ float sBias[128];
  const int t = threadIdx.x;
  // XCD-aware decode: each XCD runs 82 consecutive nt with fixed (mt,b) -> wA slab L2-resident
  const int i = blockIdx.x;            // 0..2623
  const int xcd = i & 7, j = i >> 3;   // j: 0..327
  const int mtb = j / 82, nt = j - mtb * 82;
  const int pair = xcd + 8 * mtb;      // 0..31
  const int mt = pair & 3, b = pair >> 2;
  const int m0 = mt * 128, n0 = nt * 128;
  if (t < 128) sBias[t] = bAll[m0 + t];
  f32x4 acc[4][4] = {};
  const int lane = t & 63, wv = t >> 6;
  const int srow = t >> 3;                              // staging row 0..31 (+32 per round)
  const int sseg = (((t & 7) ^ (srow & 7))) * 8;        // XOR-permuted source segment
  const int mh = (wv & 1) * 64, nh = (wv >> 1) * 64;
  const int l15 = lane & 15, q = lane >> 4;
  const int s7 = l15 & 7;                               // reader XOR key (row&7)
  u16* sAw = sA + wv * 512;                             // wave staging base (1KB/wave)
  u16* sBw = sB + wv * 512;
  const u16* gA = wA + (long)(m0 + srow) * 4608 + sseg;
  const u16* xtb = xt + ((long)b * XT_STRIDE + XT_GUARD) * 512;
  const u16* rowA = sA + (mh + l15) * 64;               // A frag row base
  const u16* rowB = sB + (nh + l15) * 64;
  for (int ks = 0; ks < 72; ++ks) {
    const int k0 = ks * 64;
    const int s = ks >> 3;                              // shift 0..8 (64 | 512)
    const int c0 = (ks & 7) * 64;
    const int off = (s / 3) * 102 + (s - (s / 3) * 3) - 103;  // (dh-1)*102 + (dw-1)
    const u16* gB = xtb + (long)(n0 + srow + off) * 512 + c0 + sseg;
    async16(gA + k0, sAw);
    async16(gA + k0 + (long)32 * 4608, sAw + 32 * 64);
    async16(gA + k0 + (long)64 * 4608, sAw + 64 * 64);
    async16(gA + k0 + (long)96 * 4608, sAw + 96 * 64);
    async16(gB,             sBw);
    async16(gB + 32 * 512,  sBw + 32 * 64);
    async16(gB + 64 * 512,  sBw + 64 * 64);
    async16(gB + 96 * 512,  sBw + 96 * 64);
    asm volatile("s_waitcnt vmcnt(0)" ::: "memory");    // drain async-LDS before barrier
    __syncthreads();
    #pragma unroll
    for (int h = 0; h < 2; ++h) {
      const int segA = ((h * 4 + q) ^ s7) * 8;          // un-swizzle: seg idx h*4+q
      bf16x8 af[4], bf[4];
      #pragma unroll
      for (int mi = 0; mi < 4; ++mi) af[mi] = *(const bf16x8*)(rowA + mi * 1024 + segA);
      #pragma unroll
      for (int ni = 0; ni < 4; ++ni) bf[ni] = *(const bf16x8*)(rowB + ni * 1024 + segA);
      #pragma unroll
      for (int mi = 0; mi < 4; ++mi)
        #pragma unroll
        for (int ni = 0; ni < 4; ++ni)
          acc[mi][ni] = __builtin_amdgcn_mfma_f32_16x16x32_bf16(af[mi], bf[ni], acc[mi][ni], 0, 0, 0);
    }
    __syncthreads();
  }
  // epilogue: bias + relu, store feat channels-last (4 consecutive o per lane -> 8B store)
  u16* fb = feat + (long)b * NPAD * 512;
  #pragma unroll
  for (int mi = 0; mi < 4; ++mi) {
    const int ol = mh + mi * 16 + q * 4;
    #pragma unroll
    for (int ni = 0; ni < 4; ++ni) {
      const int p = n0 + nh + ni * 16 + l15;
      unsigned long long pk = 0;
      #pragma unroll
      for (int r = 0; r < 4; ++r) {
        float v = acc[mi][ni][r] + sBias[ol + r];
        v = v > 0.f ? v : 0.f;
        pk |= ((unsigned long long)f2b(v)) << (16 * r);
      }
      *(unsigned long long*)(fb + (long)p * 512 + m0 + ol) = pk;
    }
  }
}

// ---------------- Heads: LDS-free MFMA — both fragments are contiguous in global layout ----------------
// A[m=a][k=c] = wH[a*512+c] (8 contiguous); B[n=p][k=c] = feat[p*512+c] (8 contiguous). No barriers.
__global__ __launch_bounds__(256) void k_head(const u16* __restrict__ feat, const u16* __restrict__ wH,
                                              const float* __restrict__ bAll, void* __restrict__ out,
                                              const int* __restrict__ flag) {
  const int f32 = *flag;
  const int t = threadIdx.x;
  const int lane = t & 63, wv = t >> 6;
  const int l15 = lane & 15, q = lane >> 4;
  const int slot = blockIdx.x * 64 + wv * 16;          // 64 p-slots per block; NPAD%64==0
  const int b = slot / NPAD, p0 = slot - b * NPAD;
  const u16* fp = feat + ((long)b * NPAD + p0 + l15) * 512 + q * 8;
  const u16* ap = wH + (long)l15 * 512 + q * 8;
  f32x4 acc[3] = {};
  #pragma unroll
  for (int ks = 0; ks < 16; ++ks) {
    const int k0 = ks * 32;
    bf16x8 bf = *(const bf16x8*)(fp + k0);
    bf16x8 a0 = *(const bf16x8*)(ap + k0);
    bf16x8 a1 = *(const bf16x8*)(ap + 16 * 512 + k0);
    bf16x8 a2 = *(const bf16x8*)(ap + 32 * 512 + k0);
    acc[0] = __builtin_amdgcn_mfma_f32_16x16x32_bf16(a0, bf, acc[0], 0, 0, 0);
    acc[1] = __builtin_amdgcn_mfma_f32_16x16x32_bf16(a1, bf, acc[1], 0, 0, 0);
    acc[2] = __builtin_amdgcn_mfma_f32_16x16x32_bf16(a2, bf, acc[2], 0, 0, 0);
  }
  const int p = p0 + l15;
  const int pr = p / 102, pc = p - pr * 102;
  if (pr < 1 || pr > 100 || pc < 1 || pc > 100) return;  // pad position
  const int h = pr - 1, w = pc - 1;
  #pragma unroll
  for (int mi = 0; mi < 3; ++mi) {
    #pragma unroll
    for (int r = 0; r < 4; ++r) {
      const int a = mi * 16 + q * 4 + r;
      if (a >= 45) continue;
      float v = acc[mi][r] + bAll[512 + a];
      long oidx;
      if (a < 9) oidx = ((long)(b * 9 + a)) * 10000 + h * 100 + w;
      else       oidx = 720000 + ((long)(b * 36 + (a - 9))) * 10000 + h * 100 + w;
      if (f32) ((float*)out)[oidx] = v;
      else     ((u16*)out)[oidx] = f2b(v);
    }
  }
}

extern "C" void kernel_launch(void* const* d_in, const int* in_sizes, int n_in,
                              void* d_out, int out_size, void* d_ws, size_t ws_size,
                              hipStream_t stream) {
  const void* x      = d_in[0];
  const void* w_rpn  = d_in[1];
  const void* b_rpn  = d_in[2];
  const void* w_cls  = d_in[3];
  const void* b_cls  = d_in[4];
  const void* w_bbox = d_in[5];
  const void* b_bbox = d_in[6];
  char* ws = (char*)d_ws;
  u16*  xt   = (u16*) (ws);                 // 8*10752*512*2 = 88,080,384
  u16*  feat = (u16*) (ws + 88080384);      // 8*10496*512*2 = 85,983,232
  u16*  wA   = (u16*) (ws + 174063616);     // 512*4608*2    =  4,718,592
  u16*  wH   = (u16*) (ws + 178782208);     // 48*512*2      =     49,152
  float* bAll= (float*)(ws + 178831360);    // 560*4
  int*  flag = (int*) (ws + 178833600);     // 4

  k_sniff<<<1, 256, 0, stream>>>((const u16*)x, flag);
  hipMemsetAsync(xt, 0, 88080384, stream);
  k_transpose<<<dim3(4, 100, 8), 256, 0, stream>>>(x, xt, flag);
  k_wA<<<1024, 256, 0, stream>>>(w_rpn, wA, flag);
  k_wH<<<96, 256, 0, stream>>>(w_cls, b_cls, w_bbox, b_bbox, b_rpn, wH, bAll, flag);
  k_conv<<<dim3(NT * 4 * 8), 256, 0, stream>>>(xt, wA, bAll, feat);
  k_head<<<dim3(NPAD * 8 / 64), 256, 0, stream>>>(feat, wH, bAll, (void*)d_out, flag);
}

// Round 5
// 810.303 us; speedup vs baseline: 1.2727x; 1.0065x over previous
//
#include <hip/hip_runtime.h>
#include <stdint.h>

typedef unsigned short u16;
typedef __bf16 bf16x8 __attribute__((ext_vector_type(8)));
typedef float f32x4 __attribute__((ext_vector_type(4)));

// Geometry
// x: [8, 512, 100, 100] (NCHW). Padded spatial grid: 102x102, flat p in [0,10404).
// xt: channels-last padded input [b][row][c] bf16, row = 128-guard + p, per-batch stride 10752 rows.
// feat: [b][p][o] bf16, per-batch stride 10496 rows (82 n-tiles * 128).
#define XT_STRIDE 10752
#define XT_GUARD  128
#define NPAD      10496
#define NT        82

__device__ __forceinline__ float b2f(u16 u) {
  union { unsigned int i; float f; } v; v.i = ((unsigned int)u) << 16; return v.f;
}
__device__ __forceinline__ u16 f2b(float f) {
  union { float f; unsigned int i; } v; v.f = f;
  unsigned int u = v.i;
  unsigned int r = u + 0x7FFFu + ((u >> 16) & 1u);  // RNE, finite inputs
  return (u16)(r >> 16);
}
__device__ __forceinline__ float ldin(const void* p, long i, int f32) {
  return f32 ? ((const float*)p)[i] : b2f(((const u16*)p)[i]);
}
// async global->LDS, 16B per lane; LDS dest = wave-uniform base + lane*16
__device__ __forceinline__ void async16(const void* g, void* l) {
  __builtin_amdgcn_global_load_lds(
      (const __attribute__((address_space(1))) unsigned int*)g,
      (__attribute__((address_space(3))) unsigned int*)l, 16, 0, 0);
}

// ---------------- P0: input dtype sniffer ----------------
__global__ __launch_bounds__(256) void k_sniff(const u16* __restrict__ x, int* __restrict__ flag) {
  __shared__ int cnt;
  if (threadIdx.x == 0) cnt = 0;
  __syncthreads();
  int c = 0;
  for (int i = threadIdx.x; i < 65536; i += 256) {
    u16 v = x[i];
    if (((v >> 7) & 0xFF) == 0xFF) c++;
  }
  atomicAdd(&cnt, c);
  __syncthreads();
  if (threadIdx.x == 0) *flag = (cnt >= 4) ? 1 : 0;
}

// ---------------- P0b: zero only the pad/guard cells of xt (replaces 88MB memset) ----------------
// Per batch: full rows [0,230) u [10430,10752)  (552 rows = guards + pr==0 + pr==101 pads)
//            plus pc==0 / pc==101 cells of interior rows pr in [1,100]  (200 rows)
// Total 48128 uint4 (16B) units per batch (~6 MB for 8 batches).
__global__ __launch_bounds__(256) void k_zero(u16* __restrict__ xt) {
  const int b = blockIdx.y;
  const int i = blockIdx.x * 256 + threadIdx.x;
  if (i >= 48128) return;
  int row, sub;
  if (i < 35328) {                       // full-row zone
    int rr = i >> 6; sub = i & 63;
    row = (rr < 230) ? rr : (10200 + rr);  // [0,230) or [10430,10752)
  } else {                               // column-pad cells
    int j = i - 35328;                   // < 12800
    int ci = j >> 6; sub = j & 63;
    int pr = (ci >> 1) + 1;              // 1..100
    row = XT_GUARD + pr * 102 + (ci & 1) * 101;
  }
  uint4 z = {0, 0, 0, 0};
  *(uint4*)(xt + ((long)b * XT_STRIDE + row) * 512 + sub * 8) = z;
}

// ---------------- P1: NCHW -> padded channels-last bf16, LDS-free register transpose ----------------
// Unit = 8 channels x 4 w. Loads: 8 x uint2 (coalesced 200B/instr across jw lanes).
// Stores: 4 x uint4 (16B) to xt rows; L2 merges partial lines within the block.
__global__ __launch_bounds__(256) void k_transpose(const void* __restrict__ x,
                                                   u16* __restrict__ xt,
                                                   const int* __restrict__ flag) {
  const int t = threadIdx.x;
  if (t >= 200) return;
  const int f32 = *flag;
  const int cb = blockIdx.x;           // 8 slabs of 64 channels
  const int h = blockIdx.y;            // 100
  const int b = blockIdx.z;            // 8
  const int co = t / 25, jw = t % 25;  // c-oct, w-quad
  const int c0 = cb * 64 + co * 8;
  u16 v[8][4];
  if (!f32) {
    const u16* src = (const u16*)x + (long)(b * 512 + c0) * 10000 + h * 100 + jw * 4;
    #pragma unroll
    for (int dc = 0; dc < 8; ++dc) {
      uint2 u = *(const uint2*)(src + (long)dc * 10000);
      const u16* pv = (const u16*)&u;
      v[dc][0] = pv[0]; v[dc][1] = pv[1]; v[dc][2] = pv[2]; v[dc][3] = pv[3];
    }
  } else {
    const float* src = (const float*)x + (long)(b * 512 + c0) * 10000 + h * 100 + jw * 4;
    #pragma unroll
    for (int dc = 0; dc < 8; ++dc) {
      float4 u = *(const float4*)(src + (long)dc * 10000);
      v[dc][0] = f2b(u.x); v[dc][1] = f2b(u.y); v[dc][2] = f2b(u.z); v[dc][3] = f2b(u.w);
    }
  }
  // p = (h+1)*102 + (1 + jw*4 + dw); interior only, pads stay k_zero'd
  u16* dst = xt + ((long)b * XT_STRIDE + XT_GUARD + (h + 1) * 102 + 1 + jw * 4) * 512 + c0;
  #pragma unroll
  for (int dw = 0; dw < 4; ++dw) {
    union { uint4 u; u16 s[8]; } pk;
    #pragma unroll
    for (int dc = 0; dc < 8; ++dc) pk.s[dc] = v[dc][dw];
    *(uint4*)(dst + (long)dw * 512) = pk.u;
  }
}

// ---------------- P2: w_rpn [o][c][3][3] -> wA [o][ s*512 + c ] bf16 ----------------
__global__ __launch_bounds__(256) void k_wA(const void* __restrict__ w_rpn,
                                            u16* __restrict__ wA,
                                            const int* __restrict__ flag) {
  const int f32 = *flag;
  const int idx = blockIdx.x * 256 + threadIdx.x;  // o*512 + c, < 262144
  const int o = idx >> 9, c = idx & 511;
  u16* dst = wA + (long)o * 4608 + c;
  #pragma unroll
  for (int s = 0; s < 9; ++s) dst[s * 512] = f2b(ldin(w_rpn, (long)idx * 9 + s, f32));
}

// ---------------- P3: head weights [48][512] bf16 + all biases fp32 ----------------
__global__ __launch_bounds__(256) void k_wH(const void* __restrict__ w_cls, const void* __restrict__ b_cls,
                                            const void* __restrict__ w_bbox, const void* __restrict__ b_bbox,
                                            const void* __restrict__ b_rpn,
                                            u16* __restrict__ wH, float* __restrict__ bAll,
                                            const int* __restrict__ flag) {
  const int f32 = *flag;
  const int idx = blockIdx.x * 256 + threadIdx.x;  // < 24576
  const int a = idx >> 9, c = idx & 511;
  float v = 0.f;
  if (a < 9) v = ldin(w_cls, a * 512 + c, f32);
  else if (a < 45) v = ldin(w_bbox, (a - 9) * 512 + c, f32);
  wH[idx] = f2b(v);
  if (idx < 512) bAll[idx] = ldin(b_rpn, idx, f32);
  if (c == 0) {
    float bv = 0.f;
    if (a < 9) bv = ldin(b_cls, a, f32);
    else if (a < 45) bv = ldin(b_bbox, a - 9, f32);
    bAll[512 + a] = bv;
  }
}

// ---------------- Conv implicit GEMM: 128x128 tile, BK=64, XCD swizzle, XOR-seg LDS ----------------
// (unchanged from round 4 — at the documented ~890 TF m97-structure plateau)
__global__ __launch_bounds__(256, 4) void k_conv(const u16* __restrict__ xt, const u16* __restrict__ wA,
                                                 const float* __restrict__ bAll, u16* __restrict__ feat) {
  __shared__ u16 sA[128 * 64];   // 16 KB
  __shared__ u16 sB[128 * 64];   // 16 KB
  __shared__ float sBias[128];
  const int t = threadIdx.x;
  const int i = blockIdx.x;            // 0..2623
  const int xcd = i & 7, j = i >> 3;   // j: 0..327
  const int mtb = j / 82, nt = j - mtb * 82;
  const int pair = xcd + 8 * mtb;      // 0..31
  const int mt = pair & 3, b = pair >> 2;
  const int m0 = mt * 128, n0 = nt * 128;
  if (t < 128) sBias[t] = bAll[m0 + t];
  f32x4 acc[4][4] = {};
  const int lane = t & 63, wv = t >> 6;
  const int srow = t >> 3;                              // staging row 0..31 (+32 per round)
  const int sseg = (((t & 7) ^ (srow & 7))) * 8;        // XOR-permuted source segment
  const int mh = (wv & 1) * 64, nh = (wv >> 1) * 64;
  const int l15 = lane & 15, q = lane >> 4;
  const int s7 = l15 & 7;                               // reader XOR key (row&7)
  u16* sAw = sA + wv * 512;                             // wave staging base (1KB/wave)
  u16* sBw = sB + wv * 512;
  const u16* gA = wA + (long)(m0 + srow) * 4608 + sseg;
  const u16* xtb = xt + ((long)b * XT_STRIDE + XT_GUARD) * 512;
  const u16* rowA = sA + (mh + l15) * 64;               // A frag row base
  const u16* rowB = sB + (nh + l15) * 64;
  for (int ks = 0; ks < 72; ++ks) {
    const int k0 = ks * 64;
    const int s = ks >> 3;                              // shift 0..8 (64 | 512)
    const int c0 = (ks & 7) * 64;
    const int off = (s / 3) * 102 + (s - (s / 3) * 3) - 103;  // (dh-1)*102 + (dw-1)
    const u16* gB = xtb + (long)(n0 + srow + off) * 512 + c0 + sseg;
    async16(gA + k0, sAw);
    async16(gA + k0 + (long)32 * 4608, sAw + 32 * 64);
    async16(gA + k0 + (long)64 * 4608, sAw + 64 * 64);
    async16(gA + k0 + (long)96 * 4608, sAw + 96 * 64);
    async16(gB,             sBw);
    async16(gB + 32 * 512,  sBw + 32 * 64);
    async16(gB + 64 * 512,  sBw + 64 * 64);
    async16(gB + 96 * 512,  sBw + 96 * 64);
    asm volatile("s_waitcnt vmcnt(0)" ::: "memory");    // drain async-LDS before barrier
    __syncthreads();
    #pragma unroll
    for (int h = 0; h < 2; ++h) {
      const int segA = ((h * 4 + q) ^ s7) * 8;          // un-swizzle: seg idx h*4+q
      bf16x8 af[4], bf[4];
      #pragma unroll
      for (int mi = 0; mi < 4; ++mi) af[mi] = *(const bf16x8*)(rowA + mi * 1024 + segA);
      #pragma unroll
      for (int ni = 0; ni < 4; ++ni) bf[ni] = *(const bf16x8*)(rowB + ni * 1024 + segA);
      #pragma unroll
      for (int mi = 0; mi < 4; ++mi)
        #pragma unroll
        for (int ni = 0; ni < 4; ++ni)
          acc[mi][ni] = __builtin_amdgcn_mfma_f32_16x16x32_bf16(af[mi], bf[ni], acc[mi][ni], 0, 0, 0);
    }
    __syncthreads();
  }
  u16* fb = feat + (long)b * NPAD * 512;
  #pragma unroll
  for (int mi = 0; mi < 4; ++mi) {
    const int ol = mh + mi * 16 + q * 4;
    #pragma unroll
    for (int ni = 0; ni < 4; ++ni) {
      const int p = n0 + nh + ni * 16 + l15;
      unsigned long long pk = 0;
      #pragma unroll
      for (int r = 0; r < 4; ++r) {
        float v = acc[mi][ni][r] + sBias[ol + r];
        v = v > 0.f ? v : 0.f;
        pk |= ((unsigned long long)f2b(v)) << (16 * r);
      }
      *(unsigned long long*)(fb + (long)p * 512 + m0 + ol) = pk;
    }
  }
}

// ---------------- Heads: LDS-free MFMA — both fragments contiguous in global layout ----------------
__global__ __launch_bounds__(256) void k_head(const u16* __restrict__ feat, const u16* __restrict__ wH,
                                              const float* __restrict__ bAll, void* __restrict__ out,
                                              const int* __restrict__ flag) {
  const int f32 = *flag;
  const int t = threadIdx.x;
  const int lane = t & 63, wv = t >> 6;
  const int l15 = lane & 15, q = lane >> 4;
  const int slot = blockIdx.x * 64 + wv * 16;          // 64 p-slots per block; NPAD%64==0
  const int b = slot / NPAD, p0 = slot - b * NPAD;
  const u16* fp = feat + ((long)b * NPAD + p0 + l15) * 512 + q * 8;
  const u16* ap = wH + (long)l15 * 512 + q * 8;
  f32x4 acc[3] = {};
  #pragma unroll
  for (int ks = 0; ks < 16; ++ks) {
    const int k0 = ks * 32;
    bf16x8 bf = *(const bf16x8*)(fp + k0);
    bf16x8 a0 = *(const bf16x8*)(ap + k0);
    bf16x8 a1 = *(const bf16x8*)(ap + 16 * 512 + k0);
    bf16x8 a2 = *(const bf16x8*)(ap + 32 * 512 + k0);
    acc[0] = __builtin_amdgcn_mfma_f32_16x16x32_bf16(a0, bf, acc[0], 0, 0, 0);
    acc[1] = __builtin_amdgcn_mfma_f32_16x16x32_bf16(a1, bf, acc[1], 0, 0, 0);
    acc[2] = __builtin_amdgcn_mfma_f32_16x16x32_bf16(a2, bf, acc[2], 0, 0, 0);
  }
  const int p = p0 + l15;
  const int pr = p / 102, pc = p - pr * 102;
  if (pr < 1 || pr > 100 || pc < 1 || pc > 100) return;  // pad position
  const int h = pr - 1, w = pc - 1;
  #pragma unroll
  for (int mi = 0; mi < 3; ++mi) {
    #pragma unroll
    for (int r = 0; r < 4; ++r) {
      const int a = mi * 16 + q * 4 + r;
      if (a >= 45) continue;
      float v = acc[mi][r] + bAll[512 + a];
      long oidx;
      if (a < 9) oidx = ((long)(b * 9 + a)) * 10000 + h * 100 + w;
      else       oidx = 720000 + ((long)(b * 36 + (a - 9))) * 10000 + h * 100 + w;
      if (f32) ((float*)out)[oidx] = v;
      else     ((u16*)out)[oidx] = f2b(v);
    }
  }
}

extern "C" void kernel_launch(void* const* d_in, const int* in_sizes, int n_in,
                              void* d_out, int out_size, void* d_ws, size_t ws_size,
                              hipStream_t stream) {
  const void* x      = d_in[0];
  const void* w_rpn  = d_in[1];
  const void* b_rpn  = d_in[2];
  const void* w_cls  = d_in[3];
  const void* b_cls  = d_in[4];
  const void* w_bbox = d_in[5];
  const void* b_bbox = d_in[6];
  char* ws = (char*)d_ws;
  u16*  xt   = (u16*) (ws);                 // 8*10752*512*2 = 88,080,384
  u16*  feat = (u16*) (ws + 88080384);      // 8*10496*512*2 = 85,983,232
  u16*  wA   = (u16*) (ws + 174063616);     // 512*4608*2    =  4,718,592
  u16*  wH   = (u16*) (ws + 178782208);     // 48*512*2      =     49,152
  float* bAll= (float*)(ws + 178831360);    // 560*4
  int*  flag = (int*) (ws + 178833600);     // 4

  k_sniff<<<1, 256, 0, stream>>>((const u16*)x, flag);
  k_zero<<<dim3(188, 8), 256, 0, stream>>>(xt);
  k_transpose<<<dim3(8, 100, 8), 256, 0, stream>>>(x, xt, flag);
  k_wA<<<1024, 256, 0, stream>>>(w_rpn, wA, flag);
  k_wH<<<96, 256, 0, stream>>>(w_cls, b_cls, w_bbox, b_bbox, b_rpn, wH, bAll, flag);
  k_conv<<<dim3(NT * 4 * 8), 256, 0, stream>>>(xt, wA, bAll, feat);
  k_head<<<dim3(NPAD * 8 / 64), 256, 0, stream>>>(feat, wH, bAll, (void*)d_out, flag);
}

// Round 8
// 754.559 us; speedup vs baseline: 1.3668x; 1.0739x over previous
//
#include <hip/hip_runtime.h>
#include <stdint.h>

typedef unsigned short u16;
typedef __bf16 bf16x8 __attribute__((ext_vector_type(8)));
typedef float f32x4 __attribute__((ext_vector_type(4)));

// Geometry
// x: [8, 512, 100, 100] NCHW (dtype runtime-detected: f32 or bf16). Padded grid 102x102.
// xt: channels-last padded input [b][row][c] bf16, row = 128-guard + p, per-batch stride 10752 rows.
// feat: [b][p][o] bf16, per-batch stride 10496 rows.
#define XT_STRIDE 10752
#define XT_GUARD  128
#define NPAD      10496
#define NT        82

__device__ __forceinline__ float b2f(u16 u) {
  union { unsigned int i; float f; } v; v.i = ((unsigned int)u) << 16; return v.f;
}
__device__ __forceinline__ u16 f2b(float f) {
  union { float f; unsigned int i; } v; v.f = f;
  unsigned int u = v.i;
  unsigned int r = u + 0x7FFFu + ((u >> 16) & 1u);  // RNE, finite inputs
  return (u16)(r >> 16);
}
__device__ __forceinline__ float ldin(const void* p, long i, int f32) {
  return f32 ? ((const float*)p)[i] : b2f(((const u16*)p)[i]);
}
// async global->LDS, 16B per lane; LDS dest = wave-uniform base + lane*16
__device__ __forceinline__ void async16(const void* g, void* l) {
  __builtin_amdgcn_global_load_lds(
      (const __attribute__((address_space(1))) unsigned int*)g,
      (__attribute__((address_space(3))) unsigned int*)l, 16, 0, 0);
}
// Wave-level dtype sniff: all waves scan the SAME 16KB window of x -> identical verdict.
// bf16 N(0,1)-scale data never has exp==0xFF halfwords; f32 low halves hit ~1/256.
__device__ __forceinline__ int sniff_is_f32(const void* x) {
  const uint4* p = (const uint4*)x;
  const int lane = threadIdx.x & 63;
  unsigned int acc = 0;
  #pragma unroll
  for (int i = 0; i < 16; ++i) {
    uint4 v = p[i * 64 + lane];
    unsigned int w0 = v.x, w1 = v.y, w2 = v.z, w3 = v.w;
    acc |= ((w0 & 0x7F80u) == 0x7F80u) | (((w0 >> 16) & 0x7F80u) == 0x7F80u);
    acc |= ((w1 & 0x7F80u) == 0x7F80u) | (((w1 >> 16) & 0x7F80u) == 0x7F80u);
    acc |= ((w2 & 0x7F80u) == 0x7F80u) | (((w2 >> 16) & 0x7F80u) == 0x7F80u);
    acc |= ((w3 & 0x7F80u) == 0x7F80u) | (((w3 >> 16) & 0x7F80u) == 0x7F80u);
  }
  return __any(acc != 0) ? 1 : 0;
}

// ---------------- k_prep: fused zero-pads + transpose + wA-shuffle + wH/bias pack ----------------
// Roles by block range (independent, disjoint writes):
//   [0,6400): transpose  (b 8 x h 100 x cb 8)
//   [6400,7904): zero xt pad/guard cells (8 x 188)
//   [7904,8928): wA shuffle (1024)
//   [8928,9024): wH + biases (96); block 8928 publishes dtype flag for k_head
__global__ __launch_bounds__(256) void k_prep(const void* __restrict__ x,
                                              const void* __restrict__ w_rpn,
                                              const void* __restrict__ b_rpn,
                                              const void* __restrict__ w_cls,
                                              const void* __restrict__ b_cls,
                                              const void* __restrict__ w_bbox,
                                              const void* __restrict__ b_bbox,
                                              u16* __restrict__ xt,
                                              u16* __restrict__ wA,
                                              u16* __restrict__ wH,
                                              float* __restrict__ bAll,
                                              int* __restrict__ flagOut) {
  const int blk = blockIdx.x;
  const int t = threadIdx.x;
  if (blk < 6400) {
    // ---- transpose: unit = 8 channels x 4 w; reg transpose, 16B stores ----
    const int f32 = sniff_is_f32(x);
    if (t >= 200) return;
    const int b = blk / 800, r = blk - b * 800;
    const int h = r >> 3, cb = r & 7;
    const int co = t / 25, jw = t % 25;
    const int c0 = cb * 64 + co * 8;
    u16 v[8][4];
    if (!f32) {
      const u16* src = (const u16*)x + (long)(b * 512 + c0) * 10000 + h * 100 + jw * 4;
      #pragma unroll
      for (int dc = 0; dc < 8; ++dc) {
        uint2 u = *(const uint2*)(src + (long)dc * 10000);
        const u16* pv = (const u16*)&u;
        v[dc][0] = pv[0]; v[dc][1] = pv[1]; v[dc][2] = pv[2]; v[dc][3] = pv[3];
      }
    } else {
      const float* src = (const float*)x + (long)(b * 512 + c0) * 10000 + h * 100 + jw * 4;
      #pragma unroll
      for (int dc = 0; dc < 8; ++dc) {
        float4 u = *(const float4*)(src + (long)dc * 10000);
        v[dc][0] = f2b(u.x); v[dc][1] = f2b(u.y); v[dc][2] = f2b(u.z); v[dc][3] = f2b(u.w);
      }
    }
    u16* dst = xt + ((long)b * XT_STRIDE + XT_GUARD + (h + 1) * 102 + 1 + jw * 4) * 512 + c0;
    #pragma unroll
    for (int dw = 0; dw < 4; ++dw) {
      union { uint4 u; u16 s[8]; } pk;
      #pragma unroll
      for (int dc = 0; dc < 8; ++dc) pk.s[dc] = v[dc][dw];
      *(uint4*)(dst + (long)dw * 512) = pk.u;
    }
  } else if (blk < 7904) {
    // ---- zero pad/guard cells of xt (48128 uint4 units per batch) ----
    const int i2 = blk - 6400;
    const int b = i2 / 188, bx = i2 - b * 188;
    const int i = bx * 256 + t;
    if (i >= 48128) return;
    int row, sub;
    if (i < 35328) {
      int rr = i >> 6; sub = i & 63;
      row = (rr < 230) ? rr : (10200 + rr);  // [0,230) or [10430,10752)
    } else {
      int j = i - 35328;
      int ci = j >> 6; sub = j & 63;
      int pr = (ci >> 1) + 1;
      row = XT_GUARD + pr * 102 + (ci & 1) * 101;
    }
    uint4 z = {0, 0, 0, 0};
    *(uint4*)(xt + ((long)b * XT_STRIDE + row) * 512 + sub * 8) = z;
  } else if (blk < 8928) {
    // ---- wA: [o][c][3][3] -> [o][s*512+c] ----
    const int f32 = sniff_is_f32(x);
    const int idx = (blk - 7904) * 256 + t;     // o*512+c
    const int o = idx >> 9, c = idx & 511;
    u16* dst = wA + (long)o * 4608 + c;
    #pragma unroll
    for (int s = 0; s < 9; ++s) dst[s * 512] = f2b(ldin(w_rpn, (long)idx * 9 + s, f32));
  } else {
    // ---- wH [48][512] (45 real + 3 zero rows) + biases + flag publish ----
    const int f32 = sniff_is_f32(x);
    const int idx = (blk - 8928) * 256 + t;     // < 24576
    const int a = idx >> 9, c = idx & 511;
    float v = 0.f;
    if (a < 9) v = ldin(w_cls, a * 512 + c, f32);
    else if (a < 45) v = ldin(w_bbox, (a - 9) * 512 + c, f32);
    wH[idx] = f2b(v);
    if (idx < 512) bAll[idx] = ldin(b_rpn, idx, f32);
    if (c == 0) {
      float bv = 0.f;
      if (a < 9) bv = ldin(b_cls, a, f32);
      else if (a < 45) bv = ldin(b_bbox, a - 9, f32);
      bAll[512 + a] = bv;
    }
    if (blk == 8928 && t == 0) *flagOut = f32;
  }
}

// ---------------- Conv implicit GEMM: 128x128 tile, BK=64, XCD swizzle, XOR-seg LDS ----------------
// (unchanged — at the documented ~890 TF m97-structure plateau; dtype-independent, all-bf16 internal)
__global__ __launch_bounds__(256, 4) void k_conv(const u16* __restrict__ xt, const u16* __restrict__ wA,
                                                 const float* __restrict__ bAll, u16* __restrict__ feat) {
  __shared__ u16 sA[128 * 64];   // 16 KB
  __shared__ u16 sB[128 * 64];   // 16 KB
  __shared__ float sBias[128];
  const int t = threadIdx.x;
  const int i = blockIdx.x;            // 0..2623
  const int xcd = i & 7, j = i >> 3;   // j: 0..327
  const int mtb = j / 82, nt = j - mtb * 82;
  const int pair = xcd + 8 * mtb;      // 0..31
  const int mt = pair & 3, b = pair >> 2;
  const int m0 = mt * 128, n0 = nt * 128;
  if (t < 128) sBias[t] = bAll[m0 + t];
  f32x4 acc[4][4] = {};
  const int lane = t & 63, wv = t >> 6;
  const int srow = t >> 3;                              // staging row 0..31 (+32 per round)
  const int sseg = (((t & 7) ^ (srow & 7))) * 8;        // XOR-permuted source segment
  const int mh = (wv & 1) * 64, nh = (wv >> 1) * 64;
  const int l15 = lane & 15, q = lane >> 4;
  const int s7 = l15 & 7;                               // reader XOR key (row&7)
  u16* sAw = sA + wv * 512;                             // wave staging base (1KB/wave)
  u16* sBw = sB + wv * 512;
  const u16* gA = wA + (long)(m0 + srow) * 4608 + sseg;
  const u16* xtb = xt + ((long)b * XT_STRIDE + XT_GUARD) * 512;
  const u16* rowA = sA + (mh + l15) * 64;               // A frag row base
  const u16* rowB = sB + (nh + l15) * 64;
  for (int ks = 0; ks < 72; ++ks) {
    const int k0 = ks * 64;
    const int s = ks >> 3;                              // shift 0..8 (64 | 512)
    const int c0 = (ks & 7) * 64;
    const int off = (s / 3) * 102 + (s - (s / 3) * 3) - 103;  // (dh-1)*102 + (dw-1)
    const u16* gB = xtb + (long)(n0 + srow + off) * 512 + c0 + sseg;
    async16(gA + k0, sAw);
    async16(gA + k0 + (long)32 * 4608, sAw + 32 * 64);
    async16(gA + k0 + (long)64 * 4608, sAw + 64 * 64);
    async16(gA + k0 + (long)96 * 4608, sAw + 96 * 64);
    async16(gB,             sBw);
    async16(gB + 32 * 512,  sBw + 32 * 64);
    async16(gB + 64 * 512,  sBw + 64 * 64);
    async16(gB + 96 * 512,  sBw + 96 * 64);
    asm volatile("s_waitcnt vmcnt(0)" ::: "memory");    // drain async-LDS before barrier
    __syncthreads();
    #pragma unroll
    for (int h = 0; h < 2; ++h) {
      const int segA = ((h * 4 + q) ^ s7) * 8;          // un-swizzle: seg idx h*4+q
      bf16x8 af[4], bf[4];
      #pragma unroll
      for (int mi = 0; mi < 4; ++mi) af[mi] = *(const bf16x8*)(rowA + mi * 1024 + segA);
      #pragma unroll
      for (int ni = 0; ni < 4; ++ni) bf[ni] = *(const bf16x8*)(rowB + ni * 1024 + segA);
      #pragma unroll
      for (int mi = 0; mi < 4; ++mi)
        #pragma unroll
        for (int ni = 0; ni < 4; ++ni)
          acc[mi][ni] = __builtin_amdgcn_mfma_f32_16x16x32_bf16(af[mi], bf[ni], acc[mi][ni], 0, 0, 0);
    }
    __syncthreads();
  }
  u16* fb = feat + (long)b * NPAD * 512;
  #pragma unroll
  for (int mi = 0; mi < 4; ++mi) {
    const int ol = mh + mi * 16 + q * 4;
    #pragma unroll
    for (int ni = 0; ni < 4; ++ni) {
      const int p = n0 + nh + ni * 16 + l15;
      unsigned long long pk = 0;
      #pragma unroll
      for (int r = 0; r < 4; ++r) {
        float v = acc[mi][ni][r] + sBias[ol + r];
        v = v > 0.f ? v : 0.f;
        pk |= ((unsigned long long)f2b(v)) << (16 * r);
      }
      *(unsigned long long*)(fb + (long)p * 512 + m0 + ol) = pk;
    }
  }
}

// ---------------- k_head: LDS-free MFMA, dual-dtype store (flag from ws) ----------------
// A[m=a][k=c] = wH[a*512+c] (8 contiguous); B[n=p][k=c] = feat[p*512+c] (8 contiguous). No barriers.
__global__ __launch_bounds__(256) void k_head(const u16* __restrict__ feat, const u16* __restrict__ wH,
                                              const float* __restrict__ bAll, void* __restrict__ out,
                                              const int* __restrict__ flag) {
  const int f32 = *flag;
  const int t = threadIdx.x;
  const int lane = t & 63, wv = t >> 6;
  const int l15 = lane & 15, q = lane >> 4;
  const int slot = blockIdx.x * 64 + wv * 16;          // 64 p-slots per block; NPAD%64==0
  const int b = slot / NPAD, p0 = slot - b * NPAD;
  const u16* fp = feat + ((long)b * NPAD + p0 + l15) * 512 + q * 8;
  const u16* ap = wH + (long)l15 * 512 + q * 8;
  f32x4 acc[3] = {};
  #pragma unroll
  for (int ks = 0; ks < 16; ++ks) {
    const int k0 = ks * 32;
    bf16x8 bf = *(const bf16x8*)(fp + k0);
    bf16x8 a0 = *(const bf16x8*)(ap + k0);
    bf16x8 a1 = *(const bf16x8*)(ap + 16 * 512 + k0);
    bf16x8 a2 = *(const bf16x8*)(ap + 32 * 512 + k0);
    acc[0] = __builtin_amdgcn_mfma_f32_16x16x32_bf16(a0, bf, acc[0], 0, 0, 0);
    acc[1] = __builtin_amdgcn_mfma_f32_16x16x32_bf16(a1, bf, acc[1], 0, 0, 0);
    acc[2] = __builtin_amdgcn_mfma_f32_16x16x32_bf16(a2, bf, acc[2], 0, 0, 0);
  }
  const int p = p0 + l15;
  const int pr = p / 102, pc = p - pr * 102;
  if (pr < 1 || pr > 100 || pc < 1 || pc > 100) return;  // pad position
  const int h = pr - 1, w = pc - 1;
  #pragma unroll
  for (int mi = 0; mi < 3; ++mi) {
    #pragma unroll
    for (int r = 0; r < 4; ++r) {
      const int a = mi * 16 + q * 4 + r;
      if (a >= 45) continue;
      float v = acc[mi][r] + bAll[512 + a];
      long oidx;
      if (a < 9) oidx = ((long)(b * 9 + a)) * 10000 + h * 100 + w;
      else       oidx = 720000 + ((long)(b * 36 + (a - 9))) * 10000 + h * 100 + w;
      if (f32) ((float*)out)[oidx] = v;
      else     ((u16*)out)[oidx] = f2b(v);
    }
  }
}

extern "C" void kernel_launch(void* const* d_in, const int* in_sizes, int n_in,
                              void* d_out, int out_size, void* d_ws, size_t ws_size,
                              hipStream_t stream) {
  const void* x      = d_in[0];
  const void* w_rpn  = d_in[1];
  const void* b_rpn  = d_in[2];
  const void* w_cls  = d_in[3];
  const void* b_cls  = d_in[4];
  const void* w_bbox = d_in[5];
  const void* b_bbox = d_in[6];
  char* ws = (char*)d_ws;
  u16*  xt   = (u16*) (ws);                 // 8*10752*512*2 = 88,080,384
  u16*  feat = (u16*) (ws + 88080384);      // 8*10496*512*2 = 85,983,232
  u16*  wA   = (u16*) (ws + 174063616);     // 512*4608*2    =  4,718,592
  u16*  wH   = (u16*) (ws + 178782208);     // 48*512*2      =     49,152
  float* bAll= (float*)(ws + 178831360);    // 560*4
  int*  flag = (int*) (ws + 178833600);     // 4

  k_prep<<<9024, 256, 0, stream>>>(x, w_rpn, b_rpn, w_cls, b_cls, w_bbox, b_bbox,
                                   xt, wA, wH, bAll, flag);
  k_conv<<<2624, 256, 0, stream>>>(xt, wA, bAll, feat);
  k_head<<<1312, 256, 0, stream>>>(feat, wH, bAll, d_out, flag);
}

// Round 9
// 666.471 us; speedup vs baseline: 1.5474x; 1.1322x over previous
//
#include <hip/hip_runtime.h>
#include <stdint.h>

typedef unsigned short u16;
typedef __bf16 bf16x8 __attribute__((ext_vector_type(8)));
typedef float f32x4 __attribute__((ext_vector_type(4)));

// Geometry
// x: [8, 512, 100, 100] NCHW (dtype runtime-detected: f32 or bf16). Padded grid 102x102.
// xt: channels-last padded input [b][row][c] bf16, row = 128-guard + p, per-batch stride 10752 rows.
// feat: [b][p][o] bf16, per-batch stride 10496 rows.
// wA: [o][cchunk*576 + s*64 + c_in]  (K-order: c-chunk major, shift s, 64 c_in)
#define XT_STRIDE 10752
#define XT_GUARD  128
#define NPAD      10496
#define NT        82

__device__ __forceinline__ float b2f(u16 u) {
  union { unsigned int i; float f; } v; v.i = ((unsigned int)u) << 16; return v.f;
}
__device__ __forceinline__ u16 f2b(float f) {
  union { float f; unsigned int i; } v; v.f = f;
  unsigned int u = v.i;
  unsigned int r = u + 0x7FFFu + ((u >> 16) & 1u);  // RNE, finite inputs
  return (u16)(r >> 16);
}
__device__ __forceinline__ float ldin(const void* p, long i, int f32) {
  return f32 ? ((const float*)p)[i] : b2f(((const u16*)p)[i]);
}
// async global->LDS, 16B per lane; LDS dest = wave-uniform base + lane*16
__device__ __forceinline__ void async16(const void* g, void* l) {
  __builtin_amdgcn_global_load_lds(
      (const __attribute__((address_space(1))) unsigned int*)g,
      (__attribute__((address_space(3))) unsigned int*)l, 16, 0, 0);
}
// Wave-level dtype sniff: all waves scan the SAME 16KB window of x -> identical verdict.
__device__ __forceinline__ int sniff_is_f32(const void* x) {
  const uint4* p = (const uint4*)x;
  const int lane = threadIdx.x & 63;
  unsigned int acc = 0;
  #pragma unroll
  for (int i = 0; i < 16; ++i) {
    uint4 v = p[i * 64 + lane];
    unsigned int w0 = v.x, w1 = v.y, w2 = v.z, w3 = v.w;
    acc |= ((w0 & 0x7F80u) == 0x7F80u) | (((w0 >> 16) & 0x7F80u) == 0x7F80u);
    acc |= ((w1 & 0x7F80u) == 0x7F80u) | (((w1 >> 16) & 0x7F80u) == 0x7F80u);
    acc |= ((w2 & 0x7F80u) == 0x7F80u) | (((w2 >> 16) & 0x7F80u) == 0x7F80u);
    acc |= ((w3 & 0x7F80u) == 0x7F80u) | (((w3 >> 16) & 0x7F80u) == 0x7F80u);
  }
  return __any(acc != 0) ? 1 : 0;
}

// ---------------- k_prep: fused zero-pads + transpose + wA-shuffle + wH/bias pack ----------------
// Roles by block range (independent, disjoint writes):
//   [0,6400): transpose  (b 8 x h 100 x cb 8)
//   [6400,7904): zero xt pad/guard cells (8 x 188)
//   [7904,8928): wA shuffle (1024)
//   [8928,9024): wH + biases (96); block 8928 publishes dtype flag for k_head
__global__ __launch_bounds__(256) void k_prep(const void* __restrict__ x,
                                              const void* __restrict__ w_rpn,
                                              const void* __restrict__ b_rpn,
                                              const void* __restrict__ w_cls,
                                              const void* __restrict__ b_cls,
                                              const void* __restrict__ w_bbox,
                                              const void* __restrict__ b_bbox,
                                              u16* __restrict__ xt,
                                              u16* __restrict__ wA,
                                              u16* __restrict__ wH,
                                              float* __restrict__ bAll,
                                              int* __restrict__ flagOut) {
  const int blk = blockIdx.x;
  const int t = threadIdx.x;
  if (blk < 6400) {
    // ---- transpose: unit = 8 channels x 4 w; reg transpose, 16B stores ----
    const int f32 = sniff_is_f32(x);
    if (t >= 200) return;
    const int b = blk / 800, r = blk - b * 800;
    const int h = r >> 3, cb = r & 7;
    const int co = t / 25, jw = t % 25;
    const int c0 = cb * 64 + co * 8;
    u16 v[8][4];
    if (!f32) {
      const u16* src = (const u16*)x + (long)(b * 512 + c0) * 10000 + h * 100 + jw * 4;
      #pragma unroll
      for (int dc = 0; dc < 8; ++dc) {
        uint2 u = *(const uint2*)(src + (long)dc * 10000);
        const u16* pv = (const u16*)&u;
        v[dc][0] = pv[0]; v[dc][1] = pv[1]; v[dc][2] = pv[2]; v[dc][3] = pv[3];
      }
    } else {
      const float* src = (const float*)x + (long)(b * 512 + c0) * 10000 + h * 100 + jw * 4;
      #pragma unroll
      for (int dc = 0; dc < 8; ++dc) {
        float4 u = *(const float4*)(src + (long)dc * 10000);
        v[dc][0] = f2b(u.x); v[dc][1] = f2b(u.y); v[dc][2] = f2b(u.z); v[dc][3] = f2b(u.w);
      }
    }
    u16* dst = xt + ((long)b * XT_STRIDE + XT_GUARD + (h + 1) * 102 + 1 + jw * 4) * 512 + c0;
    #pragma unroll
    for (int dw = 0; dw < 4; ++dw) {
      union { uint4 u; u16 s[8]; } pk;
      #pragma unroll
      for (int dc = 0; dc < 8; ++dc) pk.s[dc] = v[dc][dw];
      *(uint4*)(dst + (long)dw * 512) = pk.u;
    }
  } else if (blk < 7904) {
    // ---- zero pad/guard cells of xt (48128 uint4 units per batch) ----
    const int i2 = blk - 6400;
    const int b = i2 / 188, bx = i2 - b * 188;
    const int i = bx * 256 + t;
    if (i >= 48128) return;
    int row, sub;
    if (i < 35328) {
      int rr = i >> 6; sub = i & 63;
      row = (rr < 230) ? rr : (10200 + rr);  // [0,230) or [10430,10752)
    } else {
      int j = i - 35328;
      int ci = j >> 6; sub = j & 63;
      int pr = (ci >> 1) + 1;
      row = XT_GUARD + pr * 102 + (ci & 1) * 101;
    }
    uint4 z = {0, 0, 0, 0};
    *(uint4*)(xt + ((long)b * XT_STRIDE + row) * 512 + sub * 8) = z;
  } else if (blk < 8928) {
    // ---- wA: [o][c][3][3] -> [o][cchunk*576 + s*64 + c_in]  (s-fastest K order) ----
    const int f32 = sniff_is_f32(x);
    const int idx = (blk - 7904) * 256 + t;     // o*512+c
    const int o = idx >> 9, c = idx & 511;
    u16* dst = wA + (long)o * 4608 + (c >> 6) * 576 + (c & 63);
    #pragma unroll
    for (int s = 0; s < 9; ++s) dst[s * 64] = f2b(ldin(w_rpn, (long)idx * 9 + s, f32));
  } else {
    // ---- wH [48][512] (45 real + 3 zero rows) + biases + flag publish ----
    const int f32 = sniff_is_f32(x);
    const int idx = (blk - 8928) * 256 + t;     // < 24576
    const int a = idx >> 9, c = idx & 511;
    float v = 0.f;
    if (a < 9) v = ldin(w_cls, a * 512 + c, f32);
    else if (a < 45) v = ldin(w_bbox, (a - 9) * 512 + c, f32);
    wH[idx] = f2b(v);
    if (idx < 512) bAll[idx] = ldin(b_rpn, idx, f32);
    if (c == 0) {
      float bv = 0.f;
      if (a < 9) bv = ldin(b_cls, a, f32);
      else if (a < 45) bv = ldin(b_bbox, a - 9, f32);
      bAll[512 + a] = bv;
    }
    if (blk == 8928 && t == 0) *flagOut = f32;
  }
}

// ---------------- Conv implicit GEMM: 128x128 tile, BK=64, XCD swizzle, XOR-seg LDS ----------------
// K-order: c-chunk major, shift s FASTEST -> the 9 s-iterations of a c-chunk re-read the same
// ~40KB xt window in consecutive iterations => L2-resident => ~8/9 of B-fetch becomes L2 hits.
__global__ __launch_bounds__(256, 4) void k_conv(const u16* __restrict__ xt, const u16* __restrict__ wA,
                                                 const float* __restrict__ bAll, u16* __restrict__ feat) {
  __shared__ u16 sA[128 * 64];   // 16 KB
  __shared__ u16 sB[128 * 64];   // 16 KB
  __shared__ float sBias[128];
  const int t = threadIdx.x;
  const int i = blockIdx.x;            // 0..2623
  const int xcd = i & 7, j = i >> 3;   // j: 0..327
  const int mtb = j / 82, nt = j - mtb * 82;
  const int pair = xcd + 8 * mtb;      // 0..31
  const int mt = pair & 3, b = pair >> 2;
  const int m0 = mt * 128, n0 = nt * 128;
  if (t < 128) sBias[t] = bAll[m0 + t];
  f32x4 acc[4][4] = {};
  const int lane = t & 63, wv = t >> 6;
  const int srow = t >> 3;                              // staging row 0..31 (+32 per round)
  const int sseg = (((t & 7) ^ (srow & 7))) * 8;        // XOR-permuted source segment
  const int mh = (wv & 1) * 64, nh = (wv >> 1) * 64;
  const int l15 = lane & 15, q = lane >> 4;
  const int s7 = l15 & 7;                               // reader XOR key (row&7)
  u16* sAw = sA + wv * 512;                             // wave staging base (1KB/wave)
  u16* sBw = sB + wv * 512;
  const u16* gA = wA + (long)(m0 + srow) * 4608 + sseg;
  const u16* xtb = xt + ((long)b * XT_STRIDE + XT_GUARD) * 512;
  const u16* rowA = sA + (mh + l15) * 64;               // A frag row base
  const u16* rowB = sB + (nh + l15) * 64;
  for (int ks = 0; ks < 72; ++ks) {
    const int k0 = ks * 64;
    const int cchunk = ks / 9;
    const int s = ks - cchunk * 9;                      // shift 0..8, FASTEST
    const int c0 = cchunk * 64;
    const int off = (s / 3) * 102 + (s - (s / 3) * 3) - 103;  // (dh-1)*102 + (dw-1)
    const u16* gB = xtb + (long)(n0 + srow + off) * 512 + c0 + sseg;
    async16(gA + k0, sAw);
    async16(gA + k0 + (long)32 * 4608, sAw + 32 * 64);
    async16(gA + k0 + (long)64 * 4608, sAw + 64 * 64);
    async16(gA + k0 + (long)96 * 4608, sAw + 96 * 64);
    async16(gB,             sBw);
    async16(gB + 32 * 512,  sBw + 32 * 64);
    async16(gB + 64 * 512,  sBw + 64 * 64);
    async16(gB + 96 * 512,  sBw + 96 * 64);
    asm volatile("s_waitcnt vmcnt(0)" ::: "memory");    // drain async-LDS before barrier
    __syncthreads();
    #pragma unroll
    for (int h = 0; h < 2; ++h) {
      const int segA = ((h * 4 + q) ^ s7) * 8;          // un-swizzle: seg idx h*4+q
      bf16x8 af[4], bf[4];
      #pragma unroll
      for (int mi = 0; mi < 4; ++mi) af[mi] = *(const bf16x8*)(rowA + mi * 1024 + segA);
      #pragma unroll
      for (int ni = 0; ni < 4; ++ni) bf[ni] = *(const bf16x8*)(rowB + ni * 1024 + segA);
      #pragma unroll
      for (int mi = 0; mi < 4; ++mi)
        #pragma unroll
        for (int ni = 0; ni < 4; ++ni)
          acc[mi][ni] = __builtin_amdgcn_mfma_f32_16x16x32_bf16(af[mi], bf[ni], acc[mi][ni], 0, 0, 0);
    }
    __syncthreads();
  }
  u16* fb = feat + (long)b * NPAD * 512;
  #pragma unroll
  for (int mi = 0; mi < 4; ++mi) {
    const int ol = mh + mi * 16 + q * 4;
    #pragma unroll
    for (int ni = 0; ni < 4; ++ni) {
      const int p = n0 + nh + ni * 16 + l15;
      unsigned long long pk = 0;
      #pragma unroll
      for (int r = 0; r < 4; ++r) {
        float v = acc[mi][ni][r] + sBias[ol + r];
        v = v > 0.f ? v : 0.f;
        pk |= ((unsigned long long)f2b(v)) << (16 * r);
      }
      *(unsigned long long*)(fb + (long)p * 512 + m0 + ol) = pk;
    }
  }
}

// ---------------- k_head: LDS-free MFMA, dual-dtype store (flag from ws) ----------------
__global__ __launch_bounds__(256) void k_head(const u16* __restrict__ feat, const u16* __restrict__ wH,
                                              const float* __restrict__ bAll, void* __restrict__ out,
                                              const int* __restrict__ flag) {
  const int f32 = *flag;
  const int t = threadIdx.x;
  const int lane = t & 63, wv = t >> 6;
  const int l15 = lane & 15, q = lane >> 4;
  const int slot = blockIdx.x * 64 + wv * 16;          // 64 p-slots per block; NPAD%64==0
  const int b = slot / NPAD, p0 = slot - b * NPAD;
  const u16* fp = feat + ((long)b * NPAD + p0 + l15) * 512 + q * 8;
  const u16* ap = wH + (long)l15 * 512 + q * 8;
  f32x4 acc[3] = {};
  #pragma unroll
  for (int ks = 0; ks < 16; ++ks) {
    const int k0 = ks * 32;
    bf16x8 bf = *(const bf16x8*)(fp + k0);
    bf16x8 a0 = *(const bf16x8*)(ap + k0);
    bf16x8 a1 = *(const bf16x8*)(ap + 16 * 512 + k0);
    bf16x8 a2 = *(const bf16x8*)(ap + 32 * 512 + k0);
    acc[0] = __builtin_amdgcn_mfma_f32_16x16x32_bf16(a0, bf, acc[0], 0, 0, 0);
    acc[1] = __builtin_amdgcn_mfma_f32_16x16x32_bf16(a1, bf, acc[1], 0, 0, 0);
    acc[2] = __builtin_amdgcn_mfma_f32_16x16x32_bf16(a2, bf, acc[2], 0, 0, 0);
  }
  const int p = p0 + l15;
  const int pr = p / 102, pc = p - pr * 102;
  if (pr < 1 || pr > 100 || pc < 1 || pc > 100) return;  // pad position
  const int h = pr - 1, w = pc - 1;
  #pragma unroll
  for (int mi = 0; mi < 3; ++mi) {
    #pragma unroll
    for (int r = 0; r < 4; ++r) {
      const int a = mi * 16 + q * 4 + r;
      if (a >= 45) continue;
      float v = acc[mi][r] + bAll[512 + a];
      long oidx;
      if (a < 9) oidx = ((long)(b * 9 + a)) * 10000 + h * 100 + w;
      else       oidx = 720000 + ((long)(b * 36 + (a - 9))) * 10000 + h * 100 + w;
      if (f32) ((float*)out)[oidx] = v;
      else     ((u16*)out)[oidx] = f2b(v);
    }
  }
}

extern "C" void kernel_launch(void* const* d_in, const int* in_sizes, int n_in,
                              void* d_out, int out_size, void* d_ws, size_t ws_size,
                              hipStream_t stream) {
  const void* x      = d_in[0];
  const void* w_rpn  = d_in[1];
  const void* b_rpn  = d_in[2];
  const void* w_cls  = d_in[3];
  const void* b_cls  = d_in[4];
  const void* w_bbox = d_in[5];
  const void* b_bbox = d_in[6];
  char* ws = (char*)d_ws;
  u16*  xt   = (u16*) (ws);                 // 8*10752*512*2 = 88,080,384
  u16*  feat = (u16*) (ws + 88080384);      // 8*10496*512*2 = 85,983,232
  u16*  wA   = (u16*) (ws + 174063616);     // 512*4608*2    =  4,718,592
  u16*  wH   = (u16*) (ws + 178782208);     // 48*512*2      =     49,152
  float* bAll= (float*)(ws + 178831360);    // 560*4
  int*  flag = (int*) (ws + 178833600);     // 4

  k_prep<<<9024, 256, 0, stream>>>(x, w_rpn, b_rpn, w_cls, b_cls, w_bbox, b_bbox,
                                   xt, wA, wH, bAll, flag);
  k_conv<<<2624, 256, 0, stream>>>(xt, wA, bAll, feat);
  k_head<<<1312, 256, 0, stream>>>(feat, wH, bAll, d_out, flag);
}